// Round 1
// baseline (82.473 us; speedup 1.0000x reference)
//
#include <hip/hip_runtime.h>

// out[b,c,l] = sum_r x[b,r,l] * weight[idx[b,l], r, c] + bias[idx[b,l], c]
//   x:       (4, 256, 32, 32) fp32   flat (b*256 + r)*1024 + l
//   indexes: (4096,) int32           j in [0,8)
//   weight:  (8, 256, 256) fp32     (j*256 + r)*256 + c
//   bias:    (8, 256) fp32
//   out:     (4, 256, 32, 32) fp32  (b*256 + c)*1024 + l
//
// R13: GROUPED GEMM — eliminate R12's 8x redundant-j work. Each block:
//   1. wave 0 does a stable ballot-compaction of the 1024 tokens of its b
//      into this block's 64-token window of group j (deterministic, no
//      atomics, no extra kernel). 16 iterations over L2-hot idx.
//   2. proven R12 MFMA machinery: K-phased (K=32 x 8), double-buffered LDS
//      staging with pk2 bf16 packing, 4 waves x (64c x 64tok) via 4x4
//      16x16x32 frags; block covers all 256 c for its 64 tokens.
//   3. exact-coverage scatter epilogue (every (c,l) written exactly once).
// Work drops 8x: 128 MiB -> ~12 MiB unique traffic, 4.3 -> 0.54 GFLOP.
//
// Fragment layouts verified on HW in R8 (16x16x32 bf16):
//   A[m=lane&15][k=quad*8+i], B[k=quad*8+i][n=lane&15], D[m=quad*4+r][n=lane&15]

#define C_DIM 256
#define KD    256
#define LDPA  260      // A row stride (dwords): 260 % 32 = 4 -> 2-way (free)
#define LDPB  68       // B row stride (dwords): 68 % 32 = 4  -> 2-way (free)

typedef __attribute__((ext_vector_type(8))) short bf16x8;
typedef __attribute__((ext_vector_type(4))) float f32x4;

// pack two floats into one dword of bf16 (round-half-up, 0.5-ulp like RNE)
__device__ inline unsigned pk2(float a, float b) {
    union { float f; unsigned u; } x, y; x.f = a; y.f = b;
    return ((x.u + 0x8000u) >> 16) | ((y.u + 0x8000u) & 0xFFFF0000u);
}

__global__ __launch_bounds__(256, 2) void grouped_mfma_kernel(
    const float* __restrict__ x,
    const int*   __restrict__ idx,
    const float* __restrict__ weight,
    const float* __restrict__ bias,
    float*       __restrict__ out)
{
    const int t    = threadIdx.x;
    const int lane = t & 63;
    const int wav  = t >> 6;
    const int quad = lane >> 4;
    const int li   = lane & 15;

    // bid -> (b, j, slot). Residue (bid&7) ~ XCD: each XCD pair serves one
    // b (1 MiB x-slice + 2 MiB weight fits per-XCD 4 MiB L2). Slots are
    // interleaved across the pair so active (low) slots spread evenly.
    const int bid  = blockIdx.x;
    const int rr   = bid & 7;
    const int mm   = bid >> 3;
    const int b    = rr >> 1;
    const int j    = mm & 7;
    const int slot = (((mm >> 3) & 7) << 1) | (rr & 1);
    const int chunk0 = slot * 64;          // 16 slots * 64 = 1024 tokens max

    __shared__ unsigned Asl[2][16 * LDPA]; // [buf][k-pair][c]   (K=32/phase)
    __shared__ unsigned Bsl[2][16 * LDPB]; // [buf][k-pair][tok]
    __shared__ int toks[64];
    __shared__ int cntS;

    const float* __restrict__ wbase = weight + j * (KD * C_DIM);

    const int sc4  = (t & 63) * 4;         // A staging column (c), float4
    const int srow = t >> 6;               // 0..3

    // ---- phase-0 A (weight) loads: independent of token list, issue now ----
    float4 a0[4], a1[4];
    #pragma unroll
    for (int i = 0; i < 4; ++i) {
        const int kp = i * 4 + srow;
        const int k  = kp * 2;
        a0[i] = *(const float4*)(wbase + k * C_DIM + sc4);
        a1[i] = *(const float4*)(wbase + (k + 1) * C_DIM + sc4);
    }

    // ---- wave 0: stable compaction of tokens with idx==j into our window ----
    if (wav == 0) {
        int vv[16];
        #pragma unroll
        for (int it = 0; it < 16; ++it)
            vv[it] = idx[(b << 10) + it * 64 + lane];
        int total = 0;
        #pragma unroll
        for (int it = 0; it < 16; ++it) {
            const bool hit = (vv[it] == j);
            const unsigned long long mb = __ballot(hit);
            const int pos = total + __popcll(mb & ((1ull << lane) - 1ull));
            if (hit) {
                const int w = pos - chunk0;
                if (w >= 0 && w < 64) toks[w] = it * 64 + lane;
            }
            total += __popcll(mb);
        }
        if (lane == 0) cntS = total;
    }
    __syncthreads();

    const int cnt = cntS;
    if (chunk0 >= cnt) return;             // uniform: whole block exits
    const int cn = min(64, cnt - chunk0);  // valid tokens in this chunk

    const int tt   = t & 63;               // this thread's staged token
    const int ltok = toks[(tt < cn) ? tt : 0];
    const float* __restrict__ xb = x + ((size_t)b << 18) + ltok;
    const int kqb = srow * 4;              // this thread's k-pair base for B

    // ---- phase-0 B (gathered x) loads ----
    float xv0[4], xv1[4];
    #pragma unroll
    for (int i = 0; i < 4; ++i) {
        const int k = (kqb + i) * 2;
        xv0[i] = xb[k << 10];
        xv1[i] = xb[(k + 1) << 10];
    }

    // ---- pack + stage phase 0 into buffer 0 ----
    #pragma unroll
    for (int i = 0; i < 4; ++i) {
        const int kp = i * 4 + srow;
        uint4 pa;
        pa.x = pk2(a0[i].x, a1[i].x); pa.y = pk2(a0[i].y, a1[i].y);
        pa.z = pk2(a0[i].z, a1[i].z); pa.w = pk2(a0[i].w, a1[i].w);
        *(uint4*)&Asl[0][kp * LDPA + sc4] = pa;
    }
    #pragma unroll
    for (int i = 0; i < 4; ++i)
        Bsl[0][(kqb + i) * LDPB + tt] = pk2(xv0[i], xv1[i]);
    __syncthreads();

    f32x4 acc[4][4];
    #pragma unroll
    for (int mt = 0; mt < 4; ++mt)
        #pragma unroll
        for (int nt = 0; nt < 4; ++nt)
            acc[mt][nt] = (f32x4){0.f, 0.f, 0.f, 0.f};

    #pragma unroll
    for (int p = 0; p < 8; ++p) {
        // 1. issue next phase's global loads (in flight across compute+barrier)
        if (p < 7) {
            const int k0 = (p + 1) * 32;
            #pragma unroll
            for (int i = 0; i < 4; ++i) {
                const int kp = i * 4 + srow;
                const int k  = k0 + kp * 2;
                a0[i] = *(const float4*)(wbase + k * C_DIM + sc4);
                a1[i] = *(const float4*)(wbase + (k + 1) * C_DIM + sc4);
            }
            #pragma unroll
            for (int i = 0; i < 4; ++i) {
                const int k = k0 + (kqb + i) * 2;
                xv0[i] = xb[k << 10];
                xv1[i] = xb[(k + 1) << 10];
            }
        }

        // 2. compute K=32 from buffer p&1
        const unsigned* __restrict__ Ab = Asl[p & 1];
        const unsigned* __restrict__ Bb = Bsl[p & 1];
        const int rbase = quad * 4;
        bf16x8 af[4], bfr[4];
        #pragma unroll
        for (int mt = 0; mt < 4; ++mt) {
            const int cl = (wav << 6) + mt * 16 + li;
            uint4 u;
            u.x = Ab[(rbase + 0) * LDPA + cl];
            u.y = Ab[(rbase + 1) * LDPA + cl];
            u.z = Ab[(rbase + 2) * LDPA + cl];
            u.w = Ab[(rbase + 3) * LDPA + cl];
            af[mt] = __builtin_bit_cast(bf16x8, u);
        }
        #pragma unroll
        for (int nt = 0; nt < 4; ++nt) {
            const int ll = nt * 16 + li;
            uint4 u;
            u.x = Bb[(rbase + 0) * LDPB + ll];
            u.y = Bb[(rbase + 1) * LDPB + ll];
            u.z = Bb[(rbase + 2) * LDPB + ll];
            u.w = Bb[(rbase + 3) * LDPB + ll];
            bfr[nt] = __builtin_bit_cast(bf16x8, u);
        }
        #pragma unroll
        for (int mt = 0; mt < 4; ++mt)
            #pragma unroll
            for (int nt = 0; nt < 4; ++nt)
                acc[mt][nt] = __builtin_amdgcn_mfma_f32_16x16x32_bf16(
                    af[mt], bfr[nt], acc[mt][nt], 0, 0, 0);

        // 3. pack + write next phase into the alternate buffer, then barrier
        if (p < 7) {
            const int q = (p + 1) & 1;
            #pragma unroll
            for (int i = 0; i < 4; ++i) {
                const int kp = i * 4 + srow;
                uint4 pa;
                pa.x = pk2(a0[i].x, a1[i].x); pa.y = pk2(a0[i].y, a1[i].y);
                pa.z = pk2(a0[i].z, a1[i].z); pa.w = pk2(a0[i].w, a1[i].w);
                *(uint4*)&Asl[q][kp * LDPA + sc4] = pa;
            }
            #pragma unroll
            for (int i = 0; i < 4; ++i)
                Bsl[q][(kqb + i) * LDPB + tt] = pk2(xv0[i], xv1[i]);
            __syncthreads();
        }
    }

    // ---- epilogue: exact-coverage scatter, bias added once per (c,tok) ----
    bool keep[4];
    int  lv[4];
    #pragma unroll
    for (int nt = 0; nt < 4; ++nt) {
        const int tf = nt * 16 + li;
        keep[nt] = (tf < cn);
        lv[nt]   = keep[nt] ? toks[tf] : 0;
    }
    #pragma unroll
    for (int mt = 0; mt < 4; ++mt) {
        const int cb_ = (wav << 6) + mt * 16 + quad * 4;
        const float4 bb = *(const float4*)(bias + j * C_DIM + cb_);
        #pragma unroll
        for (int nt = 0; nt < 4; ++nt) {
            if (!keep[nt]) continue;
            float* __restrict__ op = out + ((size_t)b << 18) + ((size_t)cb_ << 10) + lv[nt];
            op[0 << 10] = acc[mt][nt][0] + bb.x;
            op[1 << 10] = acc[mt][nt][1] + bb.y;
            op[2 << 10] = acc[mt][nt][2] + bb.z;
            op[3 << 10] = acc[mt][nt][3] + bb.w;
        }
    }
}

extern "C" void kernel_launch(void* const* d_in, const int* in_sizes, int n_in,
                              void* d_out, int out_size, void* d_ws, size_t ws_size,
                              hipStream_t stream)
{
    const float* x      = (const float*)d_in[0];
    const int*   idx    = (const int*)  d_in[1];
    const float* weight = (const float*)d_in[2];
    const float* bias   = (const float*)d_in[3];
    float*       out    = (float*)      d_out;

    // grid: 512 blocks = 32 (b,j) groups x 16 chunk slots (covers worst case
    // of 1024 tokens in one group); ~half the slots early-exit on random idx.
    grouped_mfma_kernel<<<dim3(512, 1, 1), 256, 0, stream>>>(x, idx, weight, bias, out);
}

// Round 2
// 72.313 us; speedup vs baseline: 1.1405x; 1.1405x over previous
//
#include <hip/hip_runtime.h>

// out[b,c,l] = sum_r x[b,r,l] * weight[idx[b,l], r, c] + bias[idx[b,l], c]
//   x:       (4, 256, 32, 32) fp32   flat (b*256 + r)*1024 + l
//   indexes: (4096,) int32           j in [0,8)
//   weight:  (8, 256, 256) fp32     (j*256 + r)*256 + c
//   bias:    (8, 256) fp32
//   out:     (4, 256, 32, 32) fp32  (b*256 + c)*1024 + l
//
// R14: back to R12's dense redundant-j structure (R13's grouped GEMM
// collapsed to ~64 active blocks -> latency death). Two changes vs R12:
//   1. prep kernel pre-converts W and x to bf16 k-pair-packed tiles in the
//      workspace (1 MiB + 2 MiB). Kills the 8x-redundant pk2 packing VALU
//      in the hot kernel and halves global fetch bytes (128 -> 64 MiB L2).
//   2. 512-thread blocks (8 waves) on the same 128x128 tile: LDS unchanged
//      (67.6 KB, 2 blocks/CU) but 16 waves/CU = 4/SIMD (was 2/SIMD) --
//      doubles latency tolerance, which is what R12's ~20 us of stall needs.
// MFMA fragment layouts, LDP=132 bank math, k-pair dword packing, dbuf
// timeline and masked dense epilogue are R12's (HW-verified in R8).

#define C_DIM 256
#define KD    256
#define LDP   132      // LDS row stride (dwords): (kp*132 + c)%32 = (4*kp+c)%32 -> 2-way (free)

typedef __attribute__((ext_vector_type(8))) short bf16x8;
typedef __attribute__((ext_vector_type(4))) float f32x4;

// pack two floats into one dword of bf16 (round-half-up, 0.5-ulp like RNE)
__device__ inline unsigned pk2(float a, float b) {
    union { float f; unsigned u; } x, y; x.f = a; y.f = b;
    return ((x.u + 0x8000u) >> 16) | ((y.u + 0x8000u) & 0xFFFF0000u);
}

// ---- prep: fp32 -> bf16 k-pair-packed tiles in workspace ----
//   Wb[j][ct][kp][cl] : (8,2,128,128) dwords = 1 MiB ; dword = (k=2kp, k=2kp+1) at c=ct*128+cl
//   Xb[b][lt][kp][ll] : (4,8,128,128) dwords = 2 MiB ; dword = (k=2kp, k=2kp+1) at l=lt*128+ll
__global__ __launch_bounds__(256) void prep_kernel(
    const float* __restrict__ x, const float* __restrict__ w,
    unsigned* __restrict__ wbd, unsigned* __restrict__ xbd)
{
    const int g = blockIdx.x * 256 + threadIdx.x;
    if (blockIdx.x < 256) {
        const int f  = g * 4;                 // dword index into Wb
        const int j  = f >> 15;
        const int ct = (f >> 14) & 1;
        const int kp = (f >> 7) & 127;
        const int cl = f & 124;               // low 2 bits zero
        const float4 a = *(const float4*)(w + ((j * 256 + 2 * kp    ) << 8) + ct * 128 + cl);
        const float4 b = *(const float4*)(w + ((j * 256 + 2 * kp + 1) << 8) + ct * 128 + cl);
        uint4 o;
        o.x = pk2(a.x, b.x); o.y = pk2(a.y, b.y);
        o.z = pk2(a.z, b.z); o.w = pk2(a.w, b.w);
        *(uint4*)(wbd + f) = o;
    } else {
        const int g2 = g - 65536;
        const int f  = g2 * 4;                // dword index into Xb
        const int b_ = f >> 17;
        const int lt = (f >> 14) & 7;
        const int kp = (f >> 7) & 127;
        const int ll = f & 124;
        const float4 a = *(const float4*)(x + ((b_ * 256 + 2 * kp    ) << 10) + lt * 128 + ll);
        const float4 c = *(const float4*)(x + ((b_ * 256 + 2 * kp + 1) << 10) + lt * 128 + ll);
        uint4 o;
        o.x = pk2(a.x, c.x); o.y = pk2(a.y, c.y);
        o.z = pk2(a.z, c.z); o.w = pk2(a.w, c.w);
        *(uint4*)(xbd + f) = o;
    }
}

// ---- main: dense redundant-j MFMA GEMM on pre-packed bf16 tiles ----
__global__ __launch_bounds__(512, 4) void fused_mfma_kernel(
    const unsigned* __restrict__ wbd,
    const unsigned* __restrict__ xbd,
    const int*      __restrict__ idx,
    const float*    __restrict__ bias,
    float*          __restrict__ out)
{
    const int t    = threadIdx.x;
    const int lane = t & 63;
    const int wav  = t >> 6;              // 0..7
    const int quad = lane >> 4;
    const int li   = lane & 15;

    const int j    = blockIdx.z;
    const int ct   = blockIdx.x;          // c-tile of 128
    const int cb0  = ct * 128;
    const int lg0b = blockIdx.y * 128;    // global token base (never straddles b)
    const int b    = lg0b >> 10;
    const int l0b  = lg0b & 1023;
    const int lt   = (lg0b >> 7) & 7;

    __shared__ unsigned Asl[2][32 * LDP]; // [buf][kp_local][c]  (K=64/phase)
    __shared__ unsigned Bsl[2][32 * LDP]; // [buf][kp_local][l]

    const unsigned* __restrict__ wsrc = wbd + ((j * 2 + ct) << 14);  // 16384 dw per (j,ct)
    const unsigned* __restrict__ xsrc = xbd + ((b * 8 + lt) << 14);

    // staging map: u in [0,1024) covers one 32x128-dword phase tile;
    // u = i*512 + t ; kp_local = u>>5 ; c4 = (u&31)*4 ; linear src = u*4.
    const int u0 = t, u1 = 512 + t;
    const int la0 = (u0 >> 5) * LDP + (u0 & 31) * 4;
    const int la1 = (u1 >> 5) * LDP + (u1 & 31) * 4;

    const int wc = wav & 3;               // c-quarter within tile
    const int wl = wav >> 2;              // l-half within tile
    const int c_locb = wc * 32;
    const int l_locb = wl * 64;

    f32x4 acc[2][4];
    #pragma unroll
    for (int mt = 0; mt < 2; ++mt)
        #pragma unroll
        for (int nt = 0; nt < 4; ++nt)
            acc[mt][nt] = (f32x4){0.f, 0.f, 0.f, 0.f};

    // ---- prologue: load + stage phase 0 into buffer 0 ----
    uint4 a0 = *(const uint4*)(wsrc + u0 * 4);
    uint4 a1 = *(const uint4*)(wsrc + u1 * 4);
    uint4 b0 = *(const uint4*)(xsrc + u0 * 4);
    uint4 b1 = *(const uint4*)(xsrc + u1 * 4);
    *(uint4*)&Asl[0][la0] = a0;
    *(uint4*)&Asl[0][la1] = a1;
    *(uint4*)&Bsl[0][la0] = b0;
    *(uint4*)&Bsl[0][la1] = b1;
    __syncthreads();

    #pragma unroll
    for (int p = 0; p < 4; ++p) {
        // 1. issue next phase's global loads (in flight across compute)
        if (p < 3) {
            const int off = (p + 1) * 4096;
            a0 = *(const uint4*)(wsrc + off + u0 * 4);
            a1 = *(const uint4*)(wsrc + off + u1 * 4);
            b0 = *(const uint4*)(xsrc + off + u0 * 4);
            b1 = *(const uint4*)(xsrc + off + u1 * 4);
        }

        // 2. compute 2 chunks of K=32 from buffer p&1
        const unsigned* __restrict__ Ab = Asl[p & 1];
        const unsigned* __restrict__ Bb = Bsl[p & 1];
        #pragma unroll
        for (int h = 0; h < 2; ++h) {
            const int rbase = h * 16 + quad * 4;
            bf16x8 af[2], bfr[4];
            #pragma unroll
            for (int mt = 0; mt < 2; ++mt) {
                const int cl = c_locb + mt * 16 + li;
                uint4 u;
                u.x = Ab[(rbase + 0) * LDP + cl];
                u.y = Ab[(rbase + 1) * LDP + cl];
                u.z = Ab[(rbase + 2) * LDP + cl];
                u.w = Ab[(rbase + 3) * LDP + cl];
                af[mt] = __builtin_bit_cast(bf16x8, u);
            }
            #pragma unroll
            for (int nt = 0; nt < 4; ++nt) {
                const int ll = l_locb + nt * 16 + li;
                uint4 u;
                u.x = Bb[(rbase + 0) * LDP + ll];
                u.y = Bb[(rbase + 1) * LDP + ll];
                u.z = Bb[(rbase + 2) * LDP + ll];
                u.w = Bb[(rbase + 3) * LDP + ll];
                bfr[nt] = __builtin_bit_cast(bf16x8, u);
            }
            #pragma unroll
            for (int mt = 0; mt < 2; ++mt)
                #pragma unroll
                for (int nt = 0; nt < 4; ++nt)
                    acc[mt][nt] = __builtin_amdgcn_mfma_f32_16x16x32_bf16(
                        af[mt], bfr[nt], acc[mt][nt], 0, 0, 0);
        }

        // 3. stage next phase into the alternate buffer, then barrier
        if (p < 3) {
            const int q = (p + 1) & 1;
            *(uint4*)&Asl[q][la0] = a0;
            *(uint4*)&Asl[q][la1] = a1;
            *(uint4*)&Bsl[q][la0] = b0;
            *(uint4*)&Bsl[q][la1] = b1;
            __syncthreads();
        }
    }

    // ---- epilogue: masked dense scatter to out (b,c,l) ----
    bool keep[4];
    int  lgv[4];
    #pragma unroll
    for (int nt = 0; nt < 4; ++nt) {
        lgv[nt]  = lg0b + l_locb + nt * 16 + li;
        keep[nt] = (idx[lgv[nt]] == j);
    }
    #pragma unroll
    for (int mt = 0; mt < 2; ++mt) {
        const int cb = cb0 + c_locb + mt * 16 + quad * 4;
        const float4 bb = *(const float4*)(bias + j * C_DIM + cb);
        #pragma unroll
        for (int nt = 0; nt < 4; ++nt) {
            if (!keep[nt]) continue;
            float* __restrict__ op = out + (b << 18) + (cb << 10) + (lgv[nt] & 1023);
            op[0 << 10] = acc[mt][nt][0] + bb.x;
            op[1 << 10] = acc[mt][nt][1] + bb.y;
            op[2 << 10] = acc[mt][nt][2] + bb.z;
            op[3 << 10] = acc[mt][nt][3] + bb.w;
        }
    }
}

extern "C" void kernel_launch(void* const* d_in, const int* in_sizes, int n_in,
                              void* d_out, int out_size, void* d_ws, size_t ws_size,
                              hipStream_t stream)
{
    const float* x      = (const float*)d_in[0];
    const int*   idx    = (const int*)  d_in[1];
    const float* weight = (const float*)d_in[2];
    const float* bias   = (const float*)d_in[3];
    float*       out    = (float*)      d_out;

    unsigned* wbd = (unsigned*)d_ws;           // 1 MiB bf16-packed weight
    unsigned* xbd = wbd + (1 << 18);           // 2 MiB bf16-packed x

    // prep: 256 blocks convert W, 512 blocks convert x (ws is re-poisoned
    // every iteration, so prep must run in-graph before the main kernel).
    prep_kernel<<<768, 256, 0, stream>>>(x, weight, wbd, xbd);

    // main: (2 c-tiles, 32 l-tiles, 8 j) = 512 blocks of 8 waves
    // -> 2 blocks/CU (LDS 67.6 KB) = 16 waves/CU = 4 waves/SIMD.
    fused_mfma_kernel<<<dim3(2, 32, 8), 512, 0, stream>>>(wbd, xbd, idx, bias, out);
}

// Round 3
// 71.922 us; speedup vs baseline: 1.1467x; 1.0054x over previous
//
#include <hip/hip_runtime.h>

// out[b,c,l] = sum_r x[b,r,l] * weight[idx[b,l], r, c] + bias[idx[b,l], c]
//   x:       (4, 256, 32, 32) fp32   flat (b*256 + r)*1024 + l
//   indexes: (4096,) int32           j in [0,8)
//   weight:  (8, 256, 256) fp32     (j*256 + r)*256 + c
//   bias:    (8, 256) fp32
//   out:     (4, 256, 32, 32) fp32  (b*256 + c)*1024 + l
//
// R15: R14 (dense redundant-j, prep-packed bf16) was stall/LDS-issue bound,
// not byte bound. Three levers this round:
//   1. prep writes a GROUP-PACKED layout [g=kp>>2][col][w=kp&3]: one MFMA
//      fragment = 4 contiguous dwords -> ds_read_b128 (was 4x ds_read_b32).
//      Bank-balanced: bank=4*(li%8), exactly 8 lanes-slots/bank (b128 floor).
//   2. global_load_lds width=16 staging (LDS layout is linear -> legal):
//      no staging VGPRs, no ds_write, loads in flight across compute.
//   3. 8 thin K=32 phases, double-buffered: per-phase L2 service (~585 cyc)
//      < per-phase compute (~1.2k cyc) -> loads hidden behind each barrier.
// K-accumulation order and pk2 rounding identical to R14 -> same absmax.

#define C_DIM 256

typedef __attribute__((ext_vector_type(8))) short bf16x8;
typedef __attribute__((ext_vector_type(4))) float f32x4;

// pack two floats into one dword of bf16 (round-half-up, 0.5-ulp like RNE)
__device__ inline unsigned pk2(float a, float b) {
    union { float f; unsigned u; } x, y; x.f = a; y.f = b;
    return ((x.u + 0x8000u) >> 16) | ((y.u + 0x8000u) & 0xFFFF0000u);
}

__device__ inline void gl16(const unsigned* g, unsigned* l) {
    __builtin_amdgcn_global_load_lds(
        (const __attribute__((address_space(1))) unsigned*)g,
        (__attribute__((address_space(3))) unsigned*)l, 16, 0, 0);
}

// ---- prep: fp32 -> bf16 group-packed tiles in workspace ----
//   Wb uint4 index = ((j*2+ct)*32 + gg)*128 + c   (1 MiB total)
//     uint4 = k-pairs {4gg+0..3} at column c of c-tile ct (k = 8gg .. 8gg+7)
//   Xb uint4 index = ((b*8+lt)*32 + gg)*128 + ll  (2 MiB total)
__global__ __launch_bounds__(256) void prep_kernel(
    const float* __restrict__ x, const float* __restrict__ wt,
    unsigned* __restrict__ wbd, unsigned* __restrict__ xbd)
{
    const int tid = threadIdx.x;
    if (blockIdx.x < 256) {
        const int g  = blockIdx.x * 256 + tid;   // uint4 index into Wb
        const int c  = g & 127;
        const int gg = (g >> 7) & 31;
        const int ct = (g >> 12) & 1;
        const int j  = g >> 13;
        const float* src = wt + ((j * 256 + gg * 8) << 8) + ct * 128 + c;
        uint4 o;
        o.x = pk2(src[0 << 8], src[1 << 8]);
        o.y = pk2(src[2 << 8], src[3 << 8]);
        o.z = pk2(src[4 << 8], src[5 << 8]);
        o.w = pk2(src[6 << 8], src[7 << 8]);
        *(uint4*)(wbd + (size_t)g * 4) = o;
    } else {
        const int h  = (blockIdx.x - 256) * 256 + tid;  // uint4 index into Xb
        const int ll = h & 127;
        const int gg = (h >> 7) & 31;
        const int lt = (h >> 12) & 7;
        const int b  = h >> 15;
        const float* src = x + ((b * 256 + gg * 8) << 10) + lt * 128 + ll;
        uint4 o;
        o.x = pk2(src[0 << 10], src[1 << 10]);
        o.y = pk2(src[2 << 10], src[3 << 10]);
        o.z = pk2(src[4 << 10], src[5 << 10]);
        o.w = pk2(src[6 << 10], src[7 << 10]);
        *(uint4*)(xbd + (size_t)h * 4) = o;
    }
}

// ---- main: dense redundant-j MFMA GEMM on group-packed bf16 tiles ----
__global__ __launch_bounds__(512, 4) void fused_mfma_kernel(
    const unsigned* __restrict__ wbd,
    const unsigned* __restrict__ xbd,
    const int*      __restrict__ idx,
    const float*    __restrict__ bias,
    float*          __restrict__ out)
{
    const int t    = threadIdx.x;
    const int lane = t & 63;
    const int wav  = t >> 6;              // 0..7
    const int quad = lane >> 4;
    const int li   = lane & 15;

    const int j    = blockIdx.z;
    const int ct   = blockIdx.x;          // c-tile of 128
    const int cb0  = ct * 128;
    const int lg0b = blockIdx.y * 128;    // token base (never straddles b)
    const int b    = lg0b >> 10;
    const int lt   = (lg0b >> 7) & 7;

    __shared__ __align__(16) unsigned Asl[2][2048]; // [buf][g*512 + c*4 + w]
    __shared__ __align__(16) unsigned Bsl[2][2048]; // [buf][g*512 + l*4 + w]

    const unsigned* __restrict__ wsrc = wbd + ((size_t)(j * 2 + ct) << 14);
    const unsigned* __restrict__ xsrc = xbd + ((size_t)(b * 8 + lt) << 14);

    const int wc = wav & 3;               // c-quarter (32 c)
    const int wl = wav >> 2;              // l-half    (64 l)
    const int c_locb = wc * 32;
    const int l_locb = wl * 64;

    // epilogue mask prefetch (idx is L2-hot; hide the 4 scalar loads)
    bool keep[4];
    int  lgv[4];
    #pragma unroll
    for (int nt = 0; nt < 4; ++nt) {
        lgv[nt]  = lg0b + l_locb + nt * 16 + li;
        keep[nt] = (idx[lgv[nt]] == j);
    }

    f32x4 acc[2][4];
    #pragma unroll
    for (int mt = 0; mt < 2; ++mt)
        #pragma unroll
        for (int nt = 0; nt < 4; ++nt)
            acc[mt][nt] = (f32x4){0.f, 0.f, 0.f, 0.f};

    const int t4 = t * 4;                 // this thread's uint4 slot (dwords)

    // ---- prologue: DMA phase 0 into buffer 0 ----
    gl16(wsrc + t4, &Asl[0][t4]);
    gl16(xsrc + t4, &Bsl[0][t4]);
    __syncthreads();                      // compiler drains vmcnt before barrier

    #pragma unroll
    for (int p = 0; p < 8; ++p) {
        // 1. DMA next phase into the alternate buffer (in flight across compute)
        if (p < 7) {
            const int off = (p + 1) * 2048;
            gl16(wsrc + off + t4, &Asl[(p + 1) & 1][t4]);
            gl16(xsrc + off + t4, &Bsl[(p + 1) & 1][t4]);
        }

        // 2. compute K=32 from buffer p&1: frag = one ds_read_b128
        const unsigned* __restrict__ Ab = Asl[p & 1];
        const unsigned* __restrict__ Bb = Bsl[p & 1];
        bf16x8 af[2], bfr[4];
        #pragma unroll
        for (int mt = 0; mt < 2; ++mt) {
            const int cl = c_locb + mt * 16 + li;
            af[mt] = __builtin_bit_cast(bf16x8,
                *(const uint4*)&Ab[quad * 512 + cl * 4]);
        }
        #pragma unroll
        for (int nt = 0; nt < 4; ++nt) {
            const int ll = l_locb + nt * 16 + li;
            bfr[nt] = __builtin_bit_cast(bf16x8,
                *(const uint4*)&Bb[quad * 512 + ll * 4]);
        }
        #pragma unroll
        for (int mt = 0; mt < 2; ++mt)
            #pragma unroll
            for (int nt = 0; nt < 4; ++nt)
                acc[mt][nt] = __builtin_amdgcn_mfma_f32_16x16x32_bf16(
                    af[mt], bfr[nt], acc[mt][nt], 0, 0, 0);

        // 3. barrier: drains next-phase DMA + protects buffer overwrite
        if (p < 7) __syncthreads();
    }

    // ---- epilogue: masked dense scatter to out (b,c,l) ----
    #pragma unroll
    for (int mt = 0; mt < 2; ++mt) {
        const int cb = cb0 + c_locb + mt * 16 + quad * 4;
        const float4 bb = *(const float4*)(bias + j * C_DIM + cb);
        #pragma unroll
        for (int nt = 0; nt < 4; ++nt) {
            if (!keep[nt]) continue;
            float* __restrict__ op = out + (b << 18) + (cb << 10) + (lgv[nt] & 1023);
            op[0 << 10] = acc[mt][nt][0] + bb.x;
            op[1 << 10] = acc[mt][nt][1] + bb.y;
            op[2 << 10] = acc[mt][nt][2] + bb.z;
            op[3 << 10] = acc[mt][nt][3] + bb.w;
        }
    }
}

extern "C" void kernel_launch(void* const* d_in, const int* in_sizes, int n_in,
                              void* d_out, int out_size, void* d_ws, size_t ws_size,
                              hipStream_t stream)
{
    const float* x      = (const float*)d_in[0];
    const int*   idx    = (const int*)  d_in[1];
    const float* weight = (const float*)d_in[2];
    const float* bias   = (const float*)d_in[3];
    float*       out    = (float*)      d_out;

    unsigned* wbd = (unsigned*)d_ws;           // 1 MiB group-packed weight
    unsigned* xbd = wbd + (1 << 18);           // 2 MiB group-packed x

    // prep: 256 blocks convert W, 512 blocks convert x (ws is re-poisoned
    // every iteration, so prep must run in-graph before the main kernel).
    prep_kernel<<<768, 256, 0, stream>>>(x, weight, wbd, xbd);

    // main: (2 c-tiles, 32 l-tiles, 8 j) = 512 blocks of 8 waves
    // -> 2 blocks/CU; j slowest so the 8 j-copies of a (ct,y) tile share an
    // XCD residue (partial output lines merge in that XCD's L2).
    fused_mfma_kernel<<<dim3(2, 32, 8), 512, 0, stream>>>(wbd, xbd, idx, bias, out);
}

// Round 4
// 70.764 us; speedup vs baseline: 1.1655x; 1.0164x over previous
//
#include <hip/hip_runtime.h>

// out[b,c,l] = sum_r x[b,r,l] * weight[idx[b,l], r, c] + bias[idx[b,l], c]
//   x:       (4, 256, 32, 32) fp32   flat (b*256 + r)*1024 + l
//   indexes: (4096,) int32           j in [0,8)
//   weight:  (8, 256, 256) fp32     (j*256 + r)*256 + c
//   bias:    (8, 256) fp32
//   out:     (4, 256, 32, 32) fp32  (b*256 + c)*1024 + l
//
// R16: R15 + counted-vmcnt pipeline (T3/T4). R12/R14/R15 all land at 72+-1us
// despite >2x different resource models -> suspicion that dur_us is mostly
// harness floor (41us poison fill + fixed small-dispatch overhead). R16 is
// the discriminating experiment: it removes the last modeled stall -- the
// per-phase __syncthreads vmcnt(0) drain -- via a 4-buffer LDS ring with
// global_load_lds issued 2 phases ahead, s_waitcnt vmcnt(2) (never 0 in
// loop) + raw s_barrier. If dur doesn't move, the floor hypothesis is
// confirmed and we're at the harness roofline.
// Numerics (pk2 rounding, k-accumulation order) identical to R15.

#define C_DIM 256

typedef __attribute__((ext_vector_type(8))) short bf16x8;
typedef __attribute__((ext_vector_type(4))) float f32x4;

// pack two floats into one dword of bf16 (round-half-up, 0.5-ulp like RNE)
__device__ inline unsigned pk2(float a, float b) {
    union { float f; unsigned u; } x, y; x.f = a; y.f = b;
    return ((x.u + 0x8000u) >> 16) | ((y.u + 0x8000u) & 0xFFFF0000u);
}

__device__ inline void gl16(const unsigned* g, unsigned* l) {
    __builtin_amdgcn_global_load_lds(
        (const __attribute__((address_space(1))) unsigned*)g,
        (__attribute__((address_space(3))) unsigned*)l, 16, 0, 0);
}

// ---- prep: fp32 -> bf16 group-packed tiles in workspace (unchanged) ----
//   Wb uint4 index = ((j*2+ct)*32 + gg)*128 + c   (1 MiB total)
//   Xb uint4 index = ((b*8+lt)*32 + gg)*128 + ll  (2 MiB total)
__global__ __launch_bounds__(256) void prep_kernel(
    const float* __restrict__ x, const float* __restrict__ wt,
    unsigned* __restrict__ wbd, unsigned* __restrict__ xbd)
{
    const int tid = threadIdx.x;
    if (blockIdx.x < 256) {
        const int g  = blockIdx.x * 256 + tid;   // uint4 index into Wb
        const int c  = g & 127;
        const int gg = (g >> 7) & 31;
        const int ct = (g >> 12) & 1;
        const int j  = g >> 13;
        const float* src = wt + ((j * 256 + gg * 8) << 8) + ct * 128 + c;
        uint4 o;
        o.x = pk2(src[0 << 8], src[1 << 8]);
        o.y = pk2(src[2 << 8], src[3 << 8]);
        o.z = pk2(src[4 << 8], src[5 << 8]);
        o.w = pk2(src[6 << 8], src[7 << 8]);
        *(uint4*)(wbd + (size_t)g * 4) = o;
    } else {
        const int h  = (blockIdx.x - 256) * 256 + tid;  // uint4 index into Xb
        const int ll = h & 127;
        const int gg = (h >> 7) & 31;
        const int lt = (h >> 12) & 7;
        const int b  = h >> 15;
        const float* src = x + ((b * 256 + gg * 8) << 10) + lt * 128 + ll;
        uint4 o;
        o.x = pk2(src[0 << 10], src[1 << 10]);
        o.y = pk2(src[2 << 10], src[3 << 10]);
        o.z = pk2(src[4 << 10], src[5 << 10]);
        o.w = pk2(src[6 << 10], src[7 << 10]);
        *(uint4*)(xbd + (size_t)h * 4) = o;
    }
}

// ---- main: dense redundant-j MFMA GEMM, 4-buffer counted-vmcnt pipeline ----
__global__ __launch_bounds__(512, 4) void fused_mfma_kernel(
    const unsigned* __restrict__ wbd,
    const unsigned* __restrict__ xbd,
    const int*      __restrict__ idx,
    const float*    __restrict__ bias,
    float*          __restrict__ out)
{
    const int t    = threadIdx.x;
    const int lane = t & 63;
    const int wav  = t >> 6;              // 0..7
    const int quad = lane >> 4;
    const int li   = lane & 15;

    const int j    = blockIdx.z;
    const int ct   = blockIdx.x;          // c-tile of 128
    const int cb0  = ct * 128;
    const int lg0b = blockIdx.y * 128;    // token base (never straddles b)
    const int b    = lg0b >> 10;
    const int lt   = (lg0b >> 7) & 7;

    // 4-buffer ring: issue depth 2, buffer (p+2)&3 is always >=1 full phase
    // away from any buffer still being read (barrier-per-phase keeps waves
    // within one phase) -> in-loop DMA issue is hoist-proof.
    __shared__ __align__(16) unsigned Asl[4][2048]; // [buf][g*512 + c*4 + w]
    __shared__ __align__(16) unsigned Bsl[4][2048]; // [buf][g*512 + l*4 + w]

    const unsigned* __restrict__ wsrc = wbd + ((size_t)(j * 2 + ct) << 14);
    const unsigned* __restrict__ xsrc = xbd + ((size_t)(b * 8 + lt) << 14);

    const int wc = wav & 3;               // c-quarter (32 c)
    const int wl = wav >> 2;              // l-half    (64 l)
    const int c_locb = wc * 32;
    const int l_locb = wl * 64;

    const int t4 = t * 4;                 // this thread's uint4 slot (dwords)

    // ---- prologue: issue P0 then P1; order pinned so vmcnt(2) => P0 done ----
    gl16(wsrc + t4, &Asl[0][t4]);
    gl16(xsrc + t4, &Bsl[0][t4]);
    __builtin_amdgcn_sched_barrier(0);    // P0 pair issues first
    gl16(wsrc + 2048 + t4, &Asl[1][t4]);
    gl16(xsrc + 2048 + t4, &Bsl[1][t4]);
    __builtin_amdgcn_sched_barrier(0);    // then P1 pair

    // epilogue mask prefetch (after DMA issue: these retire behind P1)
    bool keep[4];
    int  lgv[4];
    #pragma unroll
    for (int nt = 0; nt < 4; ++nt) {
        lgv[nt]  = lg0b + l_locb + nt * 16 + li;
        keep[nt] = (idx[lgv[nt]] == j);
    }

    f32x4 acc[2][4];
    #pragma unroll
    for (int mt = 0; mt < 2; ++mt)
        #pragma unroll
        for (int nt = 0; nt < 4; ++nt)
            acc[mt][nt] = (f32x4){0.f, 0.f, 0.f, 0.f};

    #pragma unroll
    for (int p = 0; p < 8; ++p) {
        // 1. wait: phase p's 2 DMAs retired (>=2 newer ops may stay in
        //    flight); then barrier makes all waves' slices visible.
        if (p == 7) asm volatile("s_waitcnt vmcnt(0)" ::: "memory");
        else        asm volatile("s_waitcnt vmcnt(2)" ::: "memory");
        __builtin_amdgcn_s_barrier();

        // 2. issue phase p+2 into ring slot (p+2)&3 (freed at barrier p-1)
        if (p < 6) {
            const int off = (p + 2) * 2048;
            gl16(wsrc + off + t4, &Asl[(p + 2) & 3][t4]);
            gl16(xsrc + off + t4, &Bsl[(p + 2) & 3][t4]);
        }

        // 3. compute K=32 from ring slot p&3: frag = one ds_read_b128
        const unsigned* __restrict__ Ab = Asl[p & 3];
        const unsigned* __restrict__ Bb = Bsl[p & 3];
        bf16x8 af[2], bfr[4];
        #pragma unroll
        for (int mt = 0; mt < 2; ++mt) {
            const int cl = c_locb + mt * 16 + li;
            af[mt] = __builtin_bit_cast(bf16x8,
                *(const uint4*)&Ab[quad * 512 + cl * 4]);
        }
        #pragma unroll
        for (int nt = 0; nt < 4; ++nt) {
            const int ll = l_locb + nt * 16 + li;
            bfr[nt] = __builtin_bit_cast(bf16x8,
                *(const uint4*)&Bb[quad * 512 + ll * 4]);
        }
        #pragma unroll
        for (int mt = 0; mt < 2; ++mt)
            #pragma unroll
            for (int nt = 0; nt < 4; ++nt)
                acc[mt][nt] = __builtin_amdgcn_mfma_f32_16x16x32_bf16(
                    af[mt], bfr[nt], acc[mt][nt], 0, 0, 0);
    }

    // ---- epilogue: masked dense scatter to out (b,c,l) ----
    #pragma unroll
    for (int mt = 0; mt < 2; ++mt) {
        const int cb = cb0 + c_locb + mt * 16 + quad * 4;
        const float4 bb = *(const float4*)(bias + j * C_DIM + cb);
        #pragma unroll
        for (int nt = 0; nt < 4; ++nt) {
            if (!keep[nt]) continue;
            float* __restrict__ op = out + (b << 18) + (cb << 10) + (lgv[nt] & 1023);
            op[0 << 10] = acc[mt][nt][0] + bb.x;
            op[1 << 10] = acc[mt][nt][1] + bb.y;
            op[2 << 10] = acc[mt][nt][2] + bb.z;
            op[3 << 10] = acc[mt][nt][3] + bb.w;
        }
    }
}

extern "C" void kernel_launch(void* const* d_in, const int* in_sizes, int n_in,
                              void* d_out, int out_size, void* d_ws, size_t ws_size,
                              hipStream_t stream)
{
    const float* x      = (const float*)d_in[0];
    const int*   idx    = (const int*)  d_in[1];
    const float* weight = (const float*)d_in[2];
    const float* bias   = (const float*)d_in[3];
    float*       out    = (float*)      d_out;

    unsigned* wbd = (unsigned*)d_ws;           // 1 MiB group-packed weight
    unsigned* xbd = wbd + (1 << 18);           // 2 MiB group-packed x

    // prep: 256 blocks convert W, 512 blocks convert x (ws is re-poisoned
    // every iteration, so prep must run in-graph before the main kernel).
    prep_kernel<<<768, 256, 0, stream>>>(x, weight, wbd, xbd);

    // main: (2 c-tiles, 32 l-tiles, 8 j) = 512 blocks of 8 waves
    // -> 2 blocks/CU (LDS 64 KiB); j slowest so the 8 j-copies of a (ct,y)
    // tile share an XCD residue (partial output lines merge in that L2).
    fused_mfma_kernel<<<dim3(2, 32, 8), 512, 0, stream>>>(wbd, xbd, idx, bias, out);
}